// Round 6
// baseline (3701.562 us; speedup 1.0000x reference)
//
#include <hip/hip_runtime.h>
#include <math.h>

#define NR 1024
#define AS 264    // fwd/bwd activation LDS stride (bf16)
#define AS2 296   // color activation LDS stride (bf16)
#define IS2 0.70710678118654752f

typedef __bf16 bf16;
typedef bf16 bf16x8 __attribute__((ext_vector_type(8)));
typedef float floatx4 __attribute__((ext_vector_type(4)));

__device__ __forceinline__ float sigm(float x){ return 1.f/(1.f+expf(-x)); }
__device__ __forceinline__ float fast_sp100(float z){
    float x = 100.f*z;
    return (fmaxf(x,0.f) + __logf(1.f + __expf(-fabsf(x)))) * 0.01f;
}
__device__ __forceinline__ float fast_sigm100(float z){
    return __builtin_amdgcn_rcpf(1.f + __expf(-100.f*z));
}

// ---------- B register tile (4 col-frags of 8 bf16, hi + optional lo) ----------
template<int PASSES>
struct BT { bf16x8 h[4]; bf16x8 l[4]; };

template<int PASSES>
__device__ __forceinline__ void bt_load(BT<PASSES>& t,
    const bf16* __restrict__ Wh, const bf16* __restrict__ Wl, int ld,
    int kt, int cb, int lr, int lq)
{
    const bf16* wh = Wh + (size_t)(cb+lr)*ld + lq*8 + kt*32;
    #pragma unroll
    for (int j=0;j<4;j++) t.h[j] = *(const bf16x8*)(wh + (size_t)(j*16)*ld);
    if (PASSES==3){
        const bf16* wl = Wl + (size_t)(cb+lr)*ld + lq*8 + kt*32;
        #pragma unroll
        for (int j=0;j<4;j++) t.l[j] = *(const bf16x8*)(wl + (size_t)(j*16)*ld);
    }
}

// ---------- in-kernel GEMM with depth-1 register pipeline + cross-layer prefetch ----------
// pre holds tile kt=0 of THIS layer on entry; tile kt=0 of the NEXT layer (nWh/nWl) on exit.
template<int PASSES, int ASP, int NK>
__device__ __forceinline__ void mlp_gemm(
    BT<PASSES>& pre,
    const bf16* __restrict__ Wh, const bf16* __restrict__ Wl, int ld,
    const bf16* __restrict__ nWh, const bf16* __restrict__ nWl, int nld,
    const bf16* Ahs, const bf16* Als,
    floatx4 (&acc)[2][4], int wr, int cb, int lr, int lq)
{
    #pragma unroll
    for (int i=0;i<2;i++)
        #pragma unroll
        for (int j=0;j<4;j++) acc[i][j] = floatx4{0.f,0.f,0.f,0.f};
    BT<PASSES> cur = pre;
    #pragma unroll 1
    for (int kt=0; kt<NK; kt++){
        BT<PASSES> nxt;
        {
            bool last = (kt+1==NK);
            const bf16* ph = last? nWh : Wh;
            const bf16* pl = last? nWl : Wl;
            int pld = last? nld : ld;
            int pkt = last? 0 : kt+1;
            bt_load<PASSES>(nxt, ph, pl, pld, pkt, cb, lr, lq);
        }
        const int ab = (wr*32+lr)*ASP + kt*32 + lq*8;
        bf16x8 a0h = *(const bf16x8*)&Ahs[ab];
        bf16x8 a1h = *(const bf16x8*)&Ahs[ab+16*ASP];
        bf16x8 a0l = *(const bf16x8*)&Als[ab];
        bf16x8 a1l = *(const bf16x8*)&Als[ab+16*ASP];
        #pragma unroll
        for (int j=0;j<4;j++){
            acc[0][j] = __builtin_amdgcn_mfma_f32_16x16x32_bf16(a0h, cur.h[j], acc[0][j],0,0,0);
            acc[1][j] = __builtin_amdgcn_mfma_f32_16x16x32_bf16(a1h, cur.h[j], acc[1][j],0,0,0);
            acc[0][j] = __builtin_amdgcn_mfma_f32_16x16x32_bf16(a0l, cur.h[j], acc[0][j],0,0,0);
            acc[1][j] = __builtin_amdgcn_mfma_f32_16x16x32_bf16(a1l, cur.h[j], acc[1][j],0,0,0);
            if (PASSES==3){
                acc[0][j] = __builtin_amdgcn_mfma_f32_16x16x32_bf16(a0h, cur.l[j], acc[0][j],0,0,0);
                acc[1][j] = __builtin_amdgcn_mfma_f32_16x16x32_bf16(a1h, cur.l[j], acc[1][j],0,0,0);
            }
        }
        cur = nxt;
    }
    pre = cur;
}

// ---------- fused forward SDF MLP (embed fused; pts computed from z+rays in-kernel) ----------
struct FwdArgs {
    const float* zbuf; int zper, zstr, pmode;   // pmode 0: z=zbuf[r*zstr+k]; 1: midpoint from z (stride 128)
    const float *ro, *rd;
    const bf16 *wh[9], *wl[9]; int wld[9];
    const float* bias[9];
    const float* w8col;           // sw[8], stride 257 (col 0)
    float* sdfo; int soff, sper, sstr;
    bf16 *cinH, *cinL;            // MODE 1
    bf16* fac[8];                 // MODE 1
};

template<int MODE>  // 0 = sampling (sdf only), 1 = final (fac + cin feat + sdf)
__global__ __launch_bounds__(512,4) void k_fwd(FwdArgs a)
{
    __shared__ bf16 Ahs[64*AS], Als[64*AS];
    __shared__ float Ef[64][40];
    __shared__ float W8s[256];
    const int tid=threadIdx.x, wid=tid>>6, lane=tid&63, lr=lane&15, lq=lane>>4;
    const int wr=wid>>2, cb=(wid&3)*64;
    const int bm = blockIdx.x*64;

    BT<3> bt;
    bt_load<3>(bt, a.wh[0], a.wl[0], a.wld[0], 0, cb, lr, lq);

    if (tid<256) W8s[tid] = a.w8col[(size_t)tid*257];
    if (tid<64){
        int pg = a.soff + bm + tid;
        int r; float pm;
        if (a.pmode==0){
            r = pg / a.zper; int k = pg - r*a.zper;
            pm = a.zbuf[(size_t)r*a.zstr + k];
        } else {
            r = pg>>7; int sI = pg&127;
            float zv = a.zbuf[r*128+sI];
            float dist = (sI<127) ? a.zbuf[r*128+sI+1]-zv : 0.03125f;
            pm = zv + 0.5f*dist;
        }
        float p0 = a.ro[3*r+0]+a.rd[3*r+0]*pm;
        float p1 = a.ro[3*r+1]+a.rd[3*r+1]*pm;
        float p2 = a.ro[3*r+2]+a.rd[3*r+2]*pm;
        float vals[39];
        vals[0]=p0; vals[1]=p1; vals[2]=p2;
        float fq=1.f;
        #pragma unroll
        for (int q=0;q<6;q++){
            vals[3+6*q+0]=__sinf(fq*p0); vals[3+6*q+1]=__sinf(fq*p1); vals[3+6*q+2]=__sinf(fq*p2);
            vals[3+6*q+3]=__cosf(fq*p0); vals[3+6*q+4]=__cosf(fq*p1); vals[3+6*q+5]=__cosf(fq*p2);
            fq *= 2.f;
        }
        bf16* ah=&Ahs[tid*AS]; bf16* al=&Als[tid*AS];
        #pragma unroll
        for (int j=0;j<39;j++){
            float v=vals[j]; Ef[tid][j]=v;
            bf16 h=(bf16)v; ah[j]=h; al[j]=(bf16)(v-(float)h);
        }
        #pragma unroll
        for (int j=39;j<64;j++){ ah[j]=(bf16)0.f; al[j]=(bf16)0.f; }
    }
    __syncthreads();

    floatx4 acc[2][4];
    auto wb_act = [&](const float* bias, bf16* facp, int fld, bool l3){
        #pragma unroll
        for (int i=0;i<2;i++){
            int rbase = wr*32+i*16+lq*4;
            #pragma unroll
            for (int j=0;j<4;j++){
                int col = cb+j*16+lr;
                bool ok = (!l3) || (col<217);
                float bv = ok ? bias[col] : 0.f;
                #pragma unroll
                for (int r=0;r<4;r++){
                    if (!ok) continue;
                    int row = rbase+r;
                    float v = acc[i][j][r]+bv;
                    if (MODE==1) facp[(size_t)(bm+row)*fld+col] = (bf16)fast_sigm100(v);
                    float act = fast_sp100(v); if (l3) act *= IS2;
                    bf16 h=(bf16)act;
                    Ahs[row*AS+col]=h; Als[row*AS+col]=(bf16)(act-(float)h);
                }
            }
        }
    };

    #define LAYER(L,NKV,L3F,NXL) \
        mlp_gemm<3,AS,NKV>(bt, a.wh[L],a.wl[L],a.wld[L], \
                           a.wh[NXL],a.wl[NXL],a.wld[NXL], \
                           Ahs,Als, acc, wr,cb,lr,lq); \
        __syncthreads(); \
        wb_act(a.bias[L], MODE? a.fac[L]:(bf16*)nullptr, (L==3)?217:256, L3F); \
        __syncthreads();

    LAYER(0,2,false,1)
    LAYER(1,8,false,2)
    LAYER(2,8,false,3)
    LAYER(3,8,true,4)
    if (tid<64){
        bf16* ah=&Ahs[tid*AS]; bf16* al=&Als[tid*AS];
        #pragma unroll
        for (int c=217;c<256;c++){
            float v = Ef[tid][c-217]*IS2;
            bf16 h=(bf16)v; ah[c]=h; al[c]=(bf16)(v-(float)h);
        }
    }
    __syncthreads();
    LAYER(4,8,false,5)
    LAYER(5,8,false,6)
    LAYER(6,8,false,7)
    // L7: prefetch L8-feat tile for MODE 1, self (dummy) for MODE 0
    {
        const bf16* n8h = MODE? a.wh[8]+a.wld[8] : a.wh[7];
        const bf16* n8l = MODE? a.wl[8]+a.wld[8] : a.wl[7];
        int n8ld = MODE? a.wld[8] : a.wld[7];
        mlp_gemm<3,AS,8>(bt, a.wh[7],a.wl[7],a.wld[7], n8h,n8l,n8ld,
                         Ahs,Als, acc, wr,cb,lr,lq);
        __syncthreads();
        wb_act(a.bias[7], MODE? a.fac[7]:(bf16*)nullptr, 256, false);
        __syncthreads();
    }
    #undef LAYER

    if (MODE==1){
        // L8 feat: cols 1..256 of W8 -> cin cols 9..264
        mlp_gemm<3,AS,8>(bt, a.wh[8]+a.wld[8], a.wl[8]+a.wld[8], a.wld[8],
                         a.wh[8],a.wl[8],a.wld[8],
                         Ahs,Als, acc, wr,cb,lr,lq);
        #pragma unroll
        for (int i=0;i<2;i++){
            int rbase = wr*32+i*16+lq*4;
            #pragma unroll
            for (int j=0;j<4;j++){
                int col = cb+j*16+lr;
                float bv = a.bias[8][1+col];
                #pragma unroll
                for (int r=0;r<4;r++){
                    int row = rbase+r;
                    float v = acc[i][j][r]+bv;
                    bf16 h=(bf16)v;
                    a.cinH[(size_t)(bm+row)*272 + 9+col]=h;
                    a.cinL[(size_t)(bm+row)*272 + 9+col]=(bf16)(v-(float)h);
                }
            }
        }
    }
    // sdf = h7 . W8[:,0] + b8[0]   (8 lanes per row)
    {
        int row = wid*8 + (lane>>3);
        int kc  = (lane&7)*32;
        const bf16* ah=&Ahs[row*AS+kc]; const bf16* al=&Als[row*AS+kc];
        float s=0.f;
        #pragma unroll
        for (int c=0;c<4;c++){
            bf16x8 vh=*(const bf16x8*)(ah+c*8), vl=*(const bf16x8*)(al+c*8);
            #pragma unroll
            for (int j=0;j<8;j++) s += ((float)vh[j]+(float)vl[j]) * W8s[kc+c*8+j];
        }
        s += __shfl_xor(s,1,64); s += __shfl_xor(s,2,64); s += __shfl_xor(s,4,64);
        if ((lane&7)==0){
            int pg = a.soff + bm + row;
            a.sdfo[(pg/a.sper)*a.sstr + (pg%a.sper)] = s + a.bias[8][0];
        }
    }
}

// ---------- fused backward (sdf grad wrt pts) + emb_bwd ----------
struct BwdArgs {
    const bf16* nh[8]; int ldn[8];
    const bf16* fac[8];
    const float* w8col;
    const float* zA; const float *ro, *rd;
    bf16 *cinH, *cinL;
    float* tcos; int offp;
};

__global__ __launch_bounds__(512,4) void k_bwd(BwdArgs a)
{
    __shared__ bf16 Ahs[64*AS], Als[64*AS];
    __shared__ float detl[64][40];
    __shared__ float W8s[256];
    float* dn0 = (float*)Als;   // aliased AFTER the last gemm
    const int tid=threadIdx.x, wid=tid>>6, lane=tid&63, lr=lane&15, lq=lane>>4;
    const int wr=wid>>2, cb=(wid&3)*64;
    const int bm = blockIdx.x*64;

    BT<2> bt;
    bt_load<2>(bt, a.nh[7], nullptr, a.ldn[7], 0, cb, lr, lq);

    if (tid<256) W8s[tid] = a.w8col[(size_t)tid*257];
    __syncthreads();
    // dZ7 = W8[:,0] * fac7
    {
        int row = tid&63, c0 = (tid>>6)*32;
        const bf16* f7 = a.fac[7] + (size_t)(bm+row)*256 + c0;
        bf16* ah=&Ahs[row*AS+c0]; bf16* al=&Als[row*AS+c0];
        #pragma unroll
        for (int c=0;c<32;c+=8){
            bf16x8 fv = *(const bf16x8*)(f7+c);
            bf16x8 hv, lv;
            #pragma unroll
            for (int j=0;j<8;j++){
                float v = W8s[c0+c+j]*(float)fv[j];
                bf16 h=(bf16)v; hv[j]=h; lv[j]=(bf16)(v-(float)h);
            }
            *(bf16x8*)(ah+c)=hv; *(bf16x8*)(al+c)=lv;
        }
    }
    __syncthreads();

    floatx4 acc[2][4];
    auto wb_fac = [&](const bf16* fc, int fld){
        #pragma unroll
        for (int i=0;i<2;i++){
            int rbase = wr*32+i*16+lq*4;
            #pragma unroll
            for (int j=0;j<4;j++){
                int col = cb+j*16+lr;
                #pragma unroll
                for (int r=0;r<4;r++){
                    int row = rbase+r;
                    float v = acc[i][j][r] * (float)fc[(size_t)(bm+row)*fld+col];
                    bf16 h=(bf16)v;
                    Ahs[row*AS+col]=h; Als[row*AS+col]=(bf16)(v-(float)h);
                }
            }
        }
    };

    #define BLAYER(L,NKV,FC,FLD,NXL) \
        mlp_gemm<2,AS,NKV>(bt, a.nh[L],nullptr,a.ldn[L], \
                           a.nh[NXL],nullptr,a.ldn[NXL], \
                           Ahs,Als, acc, wr,cb,lr,lq); \
        __syncthreads(); \
        wb_fac(FC,FLD); \
        __syncthreads();

    BLAYER(7,8,a.fac[6],256,6)
    BLAYER(6,8,a.fac[5],256,5)
    BLAYER(5,8,a.fac[4],256,4)
    // din4 -> split
    mlp_gemm<2,AS,8>(bt, a.nh[4],nullptr,a.ldn[4], a.nh[3],nullptr,a.ldn[3],
                     Ahs,Als, acc, wr,cb,lr,lq);
    __syncthreads();
    #pragma unroll
    for (int i=0;i<2;i++){
        int rbase = wr*32+i*16+lq*4;
        #pragma unroll
        for (int j=0;j<4;j++){
            int col = cb+j*16+lr;
            #pragma unroll
            for (int r=0;r<4;r++){
                int row = rbase+r;
                float v = acc[i][j][r]*IS2;
                if (col<217){
                    v *= (float)a.fac[3][(size_t)(bm+row)*217+col];
                    bf16 h=(bf16)v;
                    Ahs[row*AS+col]=h; Als[row*AS+col]=(bf16)(v-(float)h);
                } else {
                    detl[row][col-217]=v;
                    Ahs[row*AS+col]=(bf16)0.f; Als[row*AS+col]=(bf16)0.f;
                }
            }
        }
    }
    __syncthreads();
    BLAYER(3,7,a.fac[2],256,2)
    BLAYER(2,8,a.fac[1],256,1)
    BLAYER(1,8,a.fac[0],256,0)
    #undef BLAYER
    // din0 (cols<39)
    mlp_gemm<2,AS,8>(bt, a.nh[0],nullptr,a.ldn[0], a.nh[0],nullptr,a.ldn[0],
                     Ahs,Als, acc, wr,cb,lr,lq);
    __syncthreads();   // all waves done reading Als -> safe to alias as dn0
    #pragma unroll
    for (int i=0;i<2;i++){
        int rbase = wr*32+i*16+lq*4;
        #pragma unroll
        for (int j=0;j<4;j++){
            int col = cb+j*16+lr;
            if (col<39){
                #pragma unroll
                for (int r=0;r<4;r++) dn0[(rbase+r)*40+col] = acc[i][j][r];
            }
        }
    }
    __syncthreads();
    if (tid<64){
        int pg = a.offp + bm + tid;
        int rI = pg>>7; int sI = pg&127;
        float zv = a.zA[rI*128+sI];
        float dist = (sI<127) ? a.zA[rI*128+sI+1]-zv : 0.03125f;
        float pm = zv + 0.5f*dist;
        float px = a.ro[3*rI+0]+a.rd[3*rI+0]*pm;
        float py = a.ro[3*rI+1]+a.rd[3*rI+1]*pm;
        float pz = a.ro[3*rI+2]+a.rd[3*rI+2]*pm;
        float g0=dn0[tid*40+0]+detl[tid][0];
        float g1=dn0[tid*40+1]+detl[tid][1];
        float g2=dn0[tid*40+2]+detl[tid][2];
        float fq=1.f;
        #pragma unroll
        for (int q=0;q<6;q++){
            int base=3+6*q;
            float ds0=dn0[tid*40+base+0]+detl[tid][base+0];
            float ds1=dn0[tid*40+base+1]+detl[tid][base+1];
            float ds2=dn0[tid*40+base+2]+detl[tid][base+2];
            float dc0=dn0[tid*40+base+3]+detl[tid][base+3];
            float dc1=dn0[tid*40+base+4]+detl[tid][base+4];
            float dc2=dn0[tid*40+base+5]+detl[tid][base+5];
            g0 += fq*(__cosf(fq*px)*ds0 - __sinf(fq*px)*dc0);
            g1 += fq*(__cosf(fq*py)*ds1 - __sinf(fq*py)*dc1);
            g2 += fq*(__cosf(fq*pz)*ds2 - __sinf(fq*pz)*dc2);
            fq *= 2.f;
        }
        float dx=a.rd[3*rI],dy=a.rd[3*rI+1],dz=a.rd[3*rI+2];
        a.tcos[pg] = dx*g0+dy*g1+dz*g2;
        float nm = fmaxf(sqrtf(g0*g0+g1*g1+g2*g2), 1e-6f);
        float vals[9] = {px,py,pz,dx,dy,dz,g0/nm,g1/nm,g2/nm};
        bf16* ch = a.cinH + (size_t)(bm+tid)*272;
        bf16* cl = a.cinL + (size_t)(bm+tid)*272;
        #pragma unroll
        for (int c=0;c<9;c++){
            float v=vals[c]; bf16 h=(bf16)v;
            ch[c]=h; cl[c]=(bf16)(v-(float)h);
        }
        #pragma unroll
        for (int c=265;c<272;c++){ ch[c]=(bf16)0.f; cl[c]=(bf16)0.f; }
    }
}

// ---------- fused color MLP ----------
struct ColArgs {
    const bf16 *cinH, *cinL;
    const bf16 *w0h,*w0l; int ld0; const float* b0;
    const bf16 *w1h,*w1l; const float* b1;
    const float* w2; const float* b2;
    float* rgb;
};

__global__ __launch_bounds__(512,4) void k_col(ColArgs a)
{
    __shared__ bf16 Ahs[64*AS2], Als[64*AS2];
    __shared__ float W2s[256*3];
    const int tid=threadIdx.x, wid=tid>>6, lane=tid&63, lr=lane&15, lq=lane>>4;
    const int wr=wid>>2, cb=(wid&3)*64;
    const int bm = blockIdx.x*64;

    BT<3> bt;
    bt_load<3>(bt, a.w0h, a.w0l, a.ld0, 0, cb, lr, lq);

    if (tid<256){ W2s[tid*3]=a.w2[tid*3]; W2s[tid*3+1]=a.w2[tid*3+1]; W2s[tid*3+2]=a.w2[tid*3+2]; }
    // stage cin (hi/lo) into LDS: 8 parts = 2 planes x 4 col-chunks of 72 (last 56 + 24 zero-pad)
    {
        int row = tid&63, sel = tid>>6;
        int plane = sel>>2, c0 = (sel&3)*72;
        const bf16* src = plane? a.cinL : a.cinH;
        bf16* dst = plane? Als : Ahs;
        const bf16* s = src + (size_t)(bm+row)*272 + c0;
        bf16* d = dst + row*AS2 + c0;
        int nv = (c0==216)? 7 : 9;
        for (int v=0;v<nv;v++) *(bf16x8*)(d+v*8) = *(const bf16x8*)(s+v*8);
        if ((sel&3)==3){
            bf16x8 z = {};
            bf16* zd = dst + row*AS2 + 272;
            #pragma unroll
            for (int v=0;v<3;v++) *(bf16x8*)(zd+v*8) = z;
        }
    }
    __syncthreads();

    floatx4 acc[2][4];
    auto wb_relu = [&](const float* bias){
        #pragma unroll
        for (int i=0;i<2;i++){
            int rbase = wr*32+i*16+lq*4;
            #pragma unroll
            for (int j=0;j<4;j++){
                int col = cb+j*16+lr;
                float bv = bias[col];
                #pragma unroll
                for (int r=0;r<4;r++){
                    int row = rbase+r;
                    float v = fmaxf(acc[i][j][r]+bv, 0.f);
                    bf16 h=(bf16)v;
                    Ahs[row*AS2+col]=h; Als[row*AS2+col]=(bf16)(v-(float)h);
                }
            }
        }
    };
    mlp_gemm<3,AS2,9>(bt, a.w0h,a.w0l,a.ld0, a.w1h,a.w1l,256,
                      Ahs,Als, acc, wr,cb,lr,lq);
    __syncthreads();
    wb_relu(a.b0);
    __syncthreads();
    mlp_gemm<3,AS2,8>(bt, a.w1h,a.w1l,256, a.w1h,a.w1l,256,
                      Ahs,Als, acc, wr,cb,lr,lq);
    __syncthreads();
    wb_relu(a.b1);
    __syncthreads();
    // rgb = sigmoid(h @ cw2 + cb2)   (8 lanes per row)
    {
        int row = wid*8 + (lane>>3);
        int kc  = (lane&7)*32;
        const bf16* ah=&Ahs[row*AS2+kc]; const bf16* al=&Als[row*AS2+kc];
        float s0=0.f,s1=0.f,s2=0.f;
        #pragma unroll
        for (int c=0;c<4;c++){
            bf16x8 vh=*(const bf16x8*)(ah+c*8), vl=*(const bf16x8*)(al+c*8);
            #pragma unroll
            for (int j=0;j<8;j++){
                float fv = (float)vh[j]+(float)vl[j];
                int k = kc+c*8+j;
                s0 += fv*W2s[k*3]; s1 += fv*W2s[k*3+1]; s2 += fv*W2s[k*3+2];
            }
        }
        #pragma unroll
        for (int m=1;m<8;m<<=1){
            s0 += __shfl_xor(s0,m,64); s1 += __shfl_xor(s1,m,64); s2 += __shfl_xor(s2,m,64);
        }
        if ((lane&7)==0){
            float* o = a.rgb + (size_t)(bm+row)*3;
            o[0]=sigm(s0+a.b2[0]); o[1]=sigm(s1+a.b2[1]); o[2]=sigm(s2+a.b2[2]);
        }
    }
}

// ---------- weight conversion ----------
struct ConvDesc { const float* src; bf16 *th, *tl, *nh; int K, N, ldt, ldn; };
struct ConvArgs { ConvDesc d[11]; };
__global__ void k_conv(ConvArgs a){
    ConvDesc cd = a.d[blockIdx.y];
    int idx = blockIdx.x*256+threadIdx.x;
    if (idx >= cd.K*cd.N) return;
    int k = idx / cd.N, n = idx - k*cd.N;
    float v = cd.src[idx];
    bf16 h = (bf16)v;
    cd.th[(size_t)n*cd.ldt + k] = h;
    cd.tl[(size_t)n*cd.ldt + k] = (bf16)(v - (float)h);
    if (cd.nh) cd.nh[(size_t)k*cd.ldn + n] = h;
}

// ---------- small kernels ----------
__global__ void k_ray_setup(const float* __restrict__ o, const float* __restrict__ d,
                            float* __restrict__ z)
{
    int r = blockIdx.x; int i = threadIdx.x;
    float ox=o[3*r],oy=o[3*r+1],oz=o[3*r+2];
    float dx=d[3*r],dy=d[3*r+1],dz=d[3*r+2];
    float a = dx*dx+dy*dy+dz*dz;
    float b = 2.f*(ox*dx+oy*dy+oz*dz);
    float mid = -b/(2.f*a);
    float nearv = fmaxf(mid-1.f, 0.05f);
    float farv = mid+1.f;
    z[r*128+i] = nearv + (farv-nearv)*((float)i/63.f);
}

__global__ void k_upsample(const float* __restrict__ o, const float* __restrict__ d,
                           const float* __restrict__ z, const float* __restrict__ sdf,
                           int S, float inv_s, float* __restrict__ new_z)
{
    int r = blockIdx.x*64+threadIdx.x; if (r>=NR) return;
    const float* zr = z + r*128;
    const float* sr = sdf + r*128;
    float ox=o[3*r],oy=o[3*r+1],oz=o[3*r+2];
    float dx=d[3*r],dy=d[3*r+1],dz=d[3*r+2];
    float w[128];
    float cdf[129];
    float wsum=0.f, T=1.f, raw_prev=0.f;
    float z0 = zr[0];
    float px=ox+dx*z0, py=oy+dy*z0, pz=oz+dz*z0;
    float r0 = sqrtf(px*px+py*py+pz*pz);
    for (int i=0;i<S-1;i++){
        float z1 = zr[i+1];
        float qx=ox+dx*z1, qy=oy+dy*z1, qz=oz+dz*z1;
        float r1 = sqrtf(qx*qx+qy*qy+qz*qz);
        bool inside = (r0<1.f)||(r1<1.f);
        float s0=sr[i], s1=sr[i+1];
        float zc = zr[i];
        float mid_sdf = 0.5f*(s0+s1);
        float raw = (s1-s0)/(z1-zc+1e-5f);
        float cv = fminf(raw, (i==0)?0.f:raw_prev);
        raw_prev = raw;
        cv = fminf(fmaxf(cv,-1000.f),0.f);
        if (!inside) cv = 0.f;
        float dist = z1-zc;
        float pe = mid_sdf - cv*dist*0.5f;
        float ne = mid_sdf + cv*dist*0.5f;
        float pc = sigm(pe*inv_s), nc = sigm(ne*inv_s);
        float alpha = (pc-nc+1e-5f)/(pc+1e-5f);
        float wi = alpha*T;
        T *= (1.f-alpha+1e-7f);
        w[i] = wi + 1e-5f;
        wsum += w[i];
        r0 = r1;
    }
    cdf[0]=0.f;
    float c=0.f;
    for (int i=0;i<S-1;i++){ c += w[i]/wsum; cdf[i+1]=c; }
    for (int j=0;j<16;j++){
        float u = 0.03125f + 0.0625f*(float)j;
        int lo=0, hi=S;
        while (lo<hi){ int m=(lo+hi)>>1; if (cdf[m]<=u) lo=m+1; else hi=m; }
        int idx = lo;
        int below = idx-1; if (below<0) below=0; if (below>S-1) below=S-1;
        int above = idx;   if (above>S-1) above=S-1;
        float c0=cdf[below], c1=cdf[above];
        float b0=zr[below], b1=zr[above];
        float dn = c1-c0; if (dn<1e-5f) dn=1.f;
        new_z[r*16+j] = b0 + (u-c0)/dn*(b1-b0);
    }
}

__global__ void k_merge(const float* __restrict__ zin, const float* __restrict__ sin_,
                        const float* __restrict__ nz, const float* __restrict__ nsdf,
                        int S, float* __restrict__ zout, float* __restrict__ sout)
{
    int r = blockIdx.x*64+threadIdx.x; if (r>=NR) return;
    const float* az = zin + r*128; const float* as = sin_ + r*128;
    const float* bz = nz + r*16;   const float* bs = nsdf + r*16;
    int i=0, j=0;
    for (int k=0;k<S+16;k++){
        bool takeA = (j>=16) || (i<S && az[i] <= bz[j]);
        if (takeA){ zout[r*128+k]=az[i]; sout[r*128+k]=as[i]; i++; }
        else      { zout[r*128+k]=bz[j]; sout[r*128+k]=bs[j]; j++; }
    }
}

__global__ void k_composite(const float* __restrict__ z, const float* __restrict__ sdfv,
                            const float* __restrict__ tcos, const float* __restrict__ rgbs,
                            const float* __restrict__ var, float* __restrict__ out)
{
    int r = blockIdx.x*64+threadIdx.x; if (r>=NR) return;
    float inv_s = expf(var[0]*10.f);
    inv_s = fminf(fmaxf(inv_s,1e-6f),1e6f);
    float T=1.f, c0=0.f, c1=0.f, c2=0.f;
    for (int sI=0;sI<128;sI++){
        float zv = z[r*128+sI];
        float dist = (sI<127)? z[r*128+sI+1]-zv : 0.03125f;
        float sd = sdfv[r*128+sI];
        float ic = fminf(tcos[r*128+sI], 0.f);
        float ep = sd - ic*dist*0.5f, en = sd + ic*dist*0.5f;
        float pc = sigm(ep*inv_s), nc = sigm(en*inv_s);
        float al = (pc-nc+1e-5f)/(pc+1e-5f);
        al = fminf(fmaxf(al,0.f),1.f);
        float wgt = al*T;
        T *= (1.f-al+1e-7f);
        c0 += wgt*rgbs[(size_t)(r*128+sI)*3+0];
        c1 += wgt*rgbs[(size_t)(r*128+sI)*3+1];
        c2 += wgt*rgbs[(size_t)(r*128+sI)*3+2];
    }
    out[3*r+0]=c0; out[3*r+1]=c1; out[3*r+2]=c2;
}

// ---------- host ----------
static inline size_t ru8(size_t x){ return (x+7)&~(size_t)7; }

extern "C" void kernel_launch(void* const* d_in, const int* in_sizes, int n_in,
                              void* d_out, int out_size, void* d_ws, size_t ws_size,
                              hipStream_t stream)
{
    const float* rays_o = (const float*)d_in[0];
    const float* rays_d = (const float*)d_in[1];
    const float* sw[9]; const float* sb[9];
    for (int l=0;l<9;l++){ sw[l]=(const float*)d_in[2+2*l]; sb[l]=(const float*)d_in[3+2*l]; }
    const float* cw0=(const float*)d_in[20]; const float* cb0=(const float*)d_in[21];
    const float* cw1=(const float*)d_in[22]; const float* cb1=(const float*)d_in[23];
    const float* cw2=(const float*)d_in[24]; const float* cb2=(const float*)d_in[25];
    const float* varp=(const float*)d_in[26];
    float* out = (float*)d_out;
    float* f = (float*)d_ws;
    size_t nf = ws_size/sizeof(float);

    size_t off = 0;
    auto AF = [&](size_t n){ float* p = f+off; off += n; return p; };
    float* zA   = AF(NR*128);
    float* zB   = AF(NR*128);
    float* sA   = AF(NR*128);
    float* sB   = AF(NR*128);
    float* nzb  = AF(NR*16);
    float* nsb  = AF(NR*16);
    float* sdfF = AF(NR*128);
    float* tcos = AF(NR*128);
    float* rgbs = AF((size_t)NR*128*3);

    off = (off+3)&~(size_t)3;   // 16B-align the bf16 pool
    bf16* wb = (bf16*)(f+off);
    size_t wboff = 0;
    auto AB = [&](size_t n){ n = ru8(n)+32; bf16* p = wb+wboff; wboff += n; return p; };

    const int inD[9]  = {39,256,256,256,256,256,256,256,256};
    const int outD[9] = {256,256,256,217,256,256,256,256,257};
    const bf16 *tH[11], *tL[11]; int ldt[11];
    const bf16 *nH[8]; int ldn_[8];
    ConvArgs ca;
    for (int l=0;l<9;l++){
        int K=inD[l], N=outD[l];
        int ld = (int)ru8(K);
        bf16* th = AB((size_t)N*ld);
        bf16* tl = AB((size_t)N*ld);
        bf16* nh = nullptr; int ldn = 0;
        if (l<8){ ldn = (int)ru8(N); nh = AB((size_t)K*ldn); nH[l]=nh; ldn_[l]=ldn; }
        tH[l]=th; tL[l]=tl; ldt[l]=ld;
        ca.d[l] = ConvDesc{ sw[l], th, tl, nh, K, N, ld, ldn };
    }
    {
        int K=265, N=256, ld=(int)ru8(K); // 272
        bf16* th = AB((size_t)N*ld); bf16* tl = AB((size_t)N*ld);
        tH[9]=th; tL[9]=tl; ldt[9]=ld;
        ca.d[9] = ConvDesc{ cw0, th, tl, nullptr, K, N, ld, 0 };
        K=256; N=256; ld=256;
        bf16* th1 = AB((size_t)N*ld); bf16* tl1 = AB((size_t)N*ld);
        tH[10]=th1; tL[10]=tl1; ldt[10]=ld;
        ca.d[10] = ConvDesc{ cw1, th1, tl1, nullptr, K, N, ld, 0 };
    }
    off += (wboff+1)/2;
    off = (off+3)&~(size_t)3;

    // chunk region (fac planes + cin planes only)
    size_t avail = (nf > off) ? nf - off : 0;
    int CHF = 131072;
    while (CHF > 1024 && (size_t)CHF*1280 > avail) CHF >>= 1;

    bf16* cb2_ = (bf16*)(f+off);
    size_t bo2 = 0;
    auto B3 = [&](size_t n){ n=ru8(n); bf16* p=cb2_+bo2; bo2+=n; return p; };
    bf16* facP[8];
    for (int l=0;l<8;l++){
        int ld = (l==3)? 217 : 256;
        facP[l] = B3((size_t)CHF*ld);
    }
    bf16* cinH = B3((size_t)CHF*272);
    bf16* cinL = B3((size_t)CHF*272);

    // ---- weight conversion ----
    k_conv<<<dim3(266,11),256,0,stream>>>(ca);
    // ---- rays + base z ----
    k_ray_setup<<<NR,64,0,stream>>>(rays_o, rays_d, zA);

    FwdArgs fa{};
    for (int l=0;l<9;l++){ fa.wh[l]=tH[l]; fa.wl[l]=tL[l]; fa.wld[l]=ldt[l]; fa.bias[l]=sb[l]; }
    fa.w8col = sw[8]; fa.ro = rays_o; fa.rd = rays_d;

    // ---- sampling: base (64 samples/ray) ----
    {
        FwdArgs s = fa;
        s.zbuf=zA; s.zper=64; s.zstr=128; s.pmode=0;
        s.sdfo = sA; s.soff=0; s.sper=64; s.sstr=128;
        k_fwd<0><<<65536/64,512,0,stream>>>(s);
    }
    // ---- 4 up-sample steps ----
    for (int it=0; it<4; it++){
        int S = 64 + 16*it;
        float* zsrc = (it&1)? zB : zA;  float* ssrc = (it&1)? sB : sA;
        float* zdst = (it&1)? zA : zB;  float* sdst = (it&1)? sA : sB;
        float inv_s = 64.f * (float)(1<<it);
        k_upsample<<<NR/64,64,0,stream>>>(rays_o, rays_d, zsrc, ssrc, S, inv_s, nzb);
        FwdArgs s = fa;
        s.zbuf=nzb; s.zper=16; s.zstr=16; s.pmode=0;
        s.sdfo = nsb; s.soff=0; s.sper=16; s.sstr=16;
        k_fwd<0><<<(NR*16)/64,512,0,stream>>>(s);
        k_merge<<<NR/64,64,0,stream>>>(zsrc, ssrc, nzb, nsb, S, zdst, sdst);
    }
    // final z in zA

    // ---- final phase ----
    for (int offp=0; offp<NR*128; offp+=CHF){
        int n = CHF;
        FwdArgs s = fa;
        s.zbuf=zA; s.pmode=1;
        s.sdfo = sdfF; s.soff=offp; s.sper=1; s.sstr=1;
        s.cinH=cinH; s.cinL=cinL;
        for (int l=0;l<8;l++) s.fac[l]=facP[l];
        k_fwd<1><<<n/64,512,0,stream>>>(s);

        BwdArgs b{};
        for (int l=0;l<8;l++){ b.nh[l]=nH[l]; b.ldn[l]=ldn_[l]; b.fac[l]=facP[l]; }
        b.w8col = sw[8]; b.zA = zA; b.ro = rays_o; b.rd = rays_d;
        b.cinH=cinH; b.cinL=cinL; b.tcos=tcos; b.offp=offp;
        k_bwd<<<n/64,512,0,stream>>>(b);

        ColArgs c{};
        c.cinH=cinH; c.cinL=cinL;
        c.w0h=tH[9]; c.w0l=tL[9]; c.ld0=ldt[9]; c.b0=cb0;
        c.w1h=tH[10]; c.w1l=tL[10]; c.b1=cb1;
        c.w2=cw2; c.b2=cb2; c.rgb = rgbs + (size_t)offp*3;
        k_col<<<n/64,512,0,stream>>>(c);
    }
    k_composite<<<NR/64,64,0,stream>>>(zA, sdfF, tcos, rgbs, varp, out);
}

// Round 8
// 2593.737 us; speedup vs baseline: 1.4271x; 1.4271x over previous
//
#include <hip/hip_runtime.h>
#include <math.h>

#define NR 1024
#define AS 264    // fwd/bwd activation LDS stride (bf16)
#define AS2 296   // color activation LDS stride (bf16)
#define IS2 0.70710678118654752f

typedef __bf16 bf16;
typedef bf16 bf16x8 __attribute__((ext_vector_type(8)));
typedef float floatx4 __attribute__((ext_vector_type(4)));

__device__ __forceinline__ float sigm(float x){ return 1.f/(1.f+expf(-x)); }
__device__ __forceinline__ float fast_sp100(float z){
    float x = 100.f*z;
    return (fmaxf(x,0.f) + __logf(1.f + __expf(-fabsf(x)))) * 0.01f;
}
__device__ __forceinline__ float fast_sigm100(float z){
    return __builtin_amdgcn_rcpf(1.f + __expf(-100.f*z));
}

// ---------- in-kernel GEMM: acc = A_lds @ W^T, B frags direct from global (L2) ----------
// 4 waves / 256 threads. Wave tile: 64 rows x 64 cols -> acc[4][4].
// PASSES 3 = AhBh + AlBh + AhBl ; PASSES 2 = AhBh + AlBh (Wl unused).
template<int PASSES, int ASP, int NK>
__device__ __forceinline__ void mlp_gemm(
    const bf16* __restrict__ Wh, const bf16* __restrict__ Wl, int ld,
    const bf16* Ahs, const bf16* Als,
    floatx4 (&acc)[4][4], int cb, int lr, int lq)
{
    #pragma unroll
    for (int i=0;i<4;i++)
        #pragma unroll
        for (int j=0;j<4;j++) acc[i][j] = floatx4{0.f,0.f,0.f,0.f};
    const bf16* wh = Wh + (size_t)(cb+lr)*ld + lq*8;
    const bf16* wl = (PASSES==3) ? (Wl + (size_t)(cb+lr)*ld + lq*8) : nullptr;
    #pragma unroll 1
    for (int kt=0; kt<NK; kt++){
        bf16x8 bh[4];
        #pragma unroll
        for (int j=0;j<4;j++) bh[j] = *(const bf16x8*)(wh + (size_t)(j*16)*ld + kt*32);
        bf16x8 bl[4];
        if (PASSES==3){
            #pragma unroll
            for (int j=0;j<4;j++) bl[j] = *(const bf16x8*)(wl + (size_t)(j*16)*ld + kt*32);
        }
        bf16x8 ah[4], al[4];
        #pragma unroll
        for (int rg=0;rg<4;rg++){
            const int ab = (rg*16+lr)*ASP + kt*32 + lq*8;
            ah[rg] = *(const bf16x8*)&Ahs[ab];
            al[rg] = *(const bf16x8*)&Als[ab];
        }
        #pragma unroll
        for (int j=0;j<4;j++){
            #pragma unroll
            for (int rg=0;rg<4;rg++){
                acc[rg][j] = __builtin_amdgcn_mfma_f32_16x16x32_bf16(ah[rg], bh[j], acc[rg][j],0,0,0);
                acc[rg][j] = __builtin_amdgcn_mfma_f32_16x16x32_bf16(al[rg], bh[j], acc[rg][j],0,0,0);
                if (PASSES==3)
                    acc[rg][j] = __builtin_amdgcn_mfma_f32_16x16x32_bf16(ah[rg], bl[j], acc[rg][j],0,0,0);
            }
        }
    }
}

// ---------- fused forward SDF MLP ----------
struct FwdArgs {
    const float* zbuf; int zper, zstr, pmode;
    const float *ro, *rd;
    const bf16 *wh[9], *wl[9]; int wld[9];
    const float* bias[9];
    const float* w8col;           // sw[8], stride 257 (col 0)
    float* sdfo; int soff, sper, sstr;
    bf16 *cinH, *cinL;            // MODE 1
    bf16* fac[8];                 // MODE 1
};

template<int MODE>  // 0 = sampling (sdf only), 1 = final (fac + cin feat + sdf)
__global__ __launch_bounds__(256,2) void k_fwd(FwdArgs a)
{
    __shared__ bf16 Ahs[64*AS], Als[64*AS];
    __shared__ float Ef[64][40];
    __shared__ float W8s[256];
    const int tid=threadIdx.x, wid=tid>>6, lane=tid&63, lr=lane&15, lq=lane>>4;
    const int cb=wid*64;
    const int bm = blockIdx.x*64;

    W8s[tid] = a.w8col[(size_t)tid*257];
    if (tid<64){
        int pg = a.soff + bm + tid;
        int r; float pm;
        if (a.pmode==0){
            r = pg / a.zper; int k = pg - r*a.zper;
            pm = a.zbuf[(size_t)r*a.zstr + k];
        } else {
            r = pg>>7; int sI = pg&127;
            float zv = a.zbuf[r*128+sI];
            float dist = (sI<127) ? a.zbuf[r*128+sI+1]-zv : 0.03125f;
            pm = zv + 0.5f*dist;
        }
        float p0 = a.ro[3*r+0]+a.rd[3*r+0]*pm;
        float p1 = a.ro[3*r+1]+a.rd[3*r+1]*pm;
        float p2 = a.ro[3*r+2]+a.rd[3*r+2]*pm;
        float vals[39];
        vals[0]=p0; vals[1]=p1; vals[2]=p2;
        float fq=1.f;
        #pragma unroll
        for (int q=0;q<6;q++){
            vals[3+6*q+0]=__sinf(fq*p0); vals[3+6*q+1]=__sinf(fq*p1); vals[3+6*q+2]=__sinf(fq*p2);
            vals[3+6*q+3]=__cosf(fq*p0); vals[3+6*q+4]=__cosf(fq*p1); vals[3+6*q+5]=__cosf(fq*p2);
            fq *= 2.f;
        }
        bf16* ah=&Ahs[tid*AS]; bf16* al=&Als[tid*AS];
        #pragma unroll
        for (int j=0;j<39;j++){
            float v=vals[j]; Ef[tid][j]=v;
            bf16 h=(bf16)v; ah[j]=h; al[j]=(bf16)(v-(float)h);
        }
        #pragma unroll
        for (int j=39;j<64;j++){ ah[j]=(bf16)0.f; al[j]=(bf16)0.f; }
    }
    __syncthreads();

    floatx4 acc[4][4];
    auto wb_act = [&](const float* bias, bf16* facp, int fld, bool l3){
        #pragma unroll
        for (int rg=0;rg<4;rg++){
            int rbase = rg*16+lq*4;
            #pragma unroll
            for (int j=0;j<4;j++){
                int col = cb+j*16+lr;
                bool ok = (!l3) || (col<217);
                float bv = ok ? bias[col] : 0.f;
                #pragma unroll
                for (int r=0;r<4;r++){
                    if (!ok) continue;
                    int row = rbase+r;
                    float v = acc[rg][j][r]+bv;
                    if (MODE==1) facp[(size_t)(bm+row)*fld+col] = (bf16)fast_sigm100(v);
                    float act = fast_sp100(v); if (l3) act *= IS2;
                    bf16 h=(bf16)act;
                    Ahs[row*AS+col]=h; Als[row*AS+col]=(bf16)(act-(float)h);
                }
            }
        }
    };

    #define LAYER(L,NKV,L3F) \
        mlp_gemm<3,AS,NKV>(a.wh[L],a.wl[L],a.wld[L], Ahs,Als, acc, cb,lr,lq); \
        __syncthreads(); \
        wb_act(a.bias[L], MODE? a.fac[L]:(bf16*)nullptr, (L==3)?217:256, L3F); \
        __syncthreads();

    LAYER(0,2,false)
    LAYER(1,8,false)
    LAYER(2,8,false)
    LAYER(3,8,true)
    if (tid<64){
        bf16* ah=&Ahs[tid*AS]; bf16* al=&Als[tid*AS];
        #pragma unroll
        for (int c=217;c<256;c++){
            float v = Ef[tid][c-217]*IS2;
            bf16 h=(bf16)v; ah[c]=h; al[c]=(bf16)(v-(float)h);
        }
    }
    __syncthreads();
    LAYER(4,8,false)
    LAYER(5,8,false)
    LAYER(6,8,false)
    LAYER(7,8,false)
    #undef LAYER

    if (MODE==1){
        // L8 feat: cols 1..256 of W8 -> cin cols 9..264
        mlp_gemm<3,AS,8>(a.wh[8]+a.wld[8], a.wl[8]+a.wld[8], a.wld[8],
                         Ahs,Als, acc, cb,lr,lq);
        #pragma unroll
        for (int rg=0;rg<4;rg++){
            int rbase = rg*16+lq*4;
            #pragma unroll
            for (int j=0;j<4;j++){
                int col = cb+j*16+lr;
                float bv = a.bias[8][1+col];
                #pragma unroll
                for (int r=0;r<4;r++){
                    int row = rbase+r;
                    float v = acc[rg][j][r]+bv;
                    bf16 h=(bf16)v;
                    a.cinH[(size_t)(bm+row)*272 + 9+col]=h;
                    a.cinL[(size_t)(bm+row)*272 + 9+col]=(bf16)(v-(float)h);
                }
            }
        }
    }
    // sdf = h7 . W8[:,0] + b8[0]   (4 lanes per row)
    {
        int row = wid*16 + (lane>>2);
        int kc  = (lane&3)*64;
        const bf16* ah=&Ahs[row*AS+kc]; const bf16* al=&Als[row*AS+kc];
        float s=0.f;
        #pragma unroll
        for (int c=0;c<8;c++){
            bf16x8 vh=*(const bf16x8*)(ah+c*8), vl=*(const bf16x8*)(al+c*8);
            #pragma unroll
            for (int j=0;j<8;j++) s += ((float)vh[j]+(float)vl[j]) * W8s[kc+c*8+j];
        }
        s += __shfl_xor(s,1,64); s += __shfl_xor(s,2,64);
        if ((lane&3)==0){
            int pg = a.soff + bm + row;
            a.sdfo[(pg/a.sper)*a.sstr + (pg%a.sper)] = s + a.bias[8][0];
        }
    }
}

// ---------- fused backward (sdf grad wrt pts) + emb_bwd ----------
struct BwdArgs {
    const bf16* nh[8]; int ldn[8];
    const bf16* fac[8];
    const float* w8col;
    const float* zA; const float *ro, *rd;
    bf16 *cinH, *cinL;
    float* tcos; int offp;
};

__global__ __launch_bounds__(256,2) void k_bwd(BwdArgs a)
{
    __shared__ bf16 Ahs[64*AS], Als[64*AS];
    __shared__ float detl[64][40];
    __shared__ float W8s[256];
    float* dn0 = (float*)Als;   // aliased AFTER the last gemm
    const int tid=threadIdx.x, wid=tid>>6, lane=tid&63, lr=lane&15, lq=lane>>4;
    const int cb=wid*64;
    const int bm = blockIdx.x*64;

    W8s[tid] = a.w8col[(size_t)tid*257];
    __syncthreads();
    // dZ7 = W8[:,0] * fac7
    {
        int row = tid&63, c0 = (tid>>6)*64;
        const bf16* f7 = a.fac[7] + (size_t)(bm+row)*256 + c0;
        bf16* ah=&Ahs[row*AS+c0]; bf16* al=&Als[row*AS+c0];
        #pragma unroll
        for (int c=0;c<64;c+=8){
            bf16x8 fv = *(const bf16x8*)(f7+c);
            bf16x8 hv, lv;
            #pragma unroll
            for (int j=0;j<8;j++){
                float v = W8s[c0+c+j]*(float)fv[j];
                bf16 h=(bf16)v; hv[j]=h; lv[j]=(bf16)(v-(float)h);
            }
            *(bf16x8*)(ah+c)=hv; *(bf16x8*)(al+c)=lv;
        }
    }
    __syncthreads();

    floatx4 acc[4][4];
    auto wb_fac = [&](const bf16* fc, int fld){
        #pragma unroll
        for (int rg=0;rg<4;rg++){
            int rbase = rg*16+lq*4;
            #pragma unroll
            for (int j=0;j<4;j++){
                int col = cb+j*16+lr;
                #pragma unroll
                for (int r=0;r<4;r++){
                    int row = rbase+r;
                    float v = acc[rg][j][r] * (float)fc[(size_t)(bm+row)*fld+col];
                    bf16 h=(bf16)v;
                    Ahs[row*AS+col]=h; Als[row*AS+col]=(bf16)(v-(float)h);
                }
            }
        }
    };

    #define BLAYER(L,NKV,FC,FLD) \
        mlp_gemm<2,AS,NKV>(a.nh[L],nullptr,a.ldn[L], Ahs,Als, acc, cb,lr,lq); \
        __syncthreads(); \
        wb_fac(FC,FLD); \
        __syncthreads();

    BLAYER(7,8,a.fac[6],256)
    BLAYER(6,8,a.fac[5],256)
    BLAYER(5,8,a.fac[4],256)
    // din4 -> split
    mlp_gemm<2,AS,8>(a.nh[4],nullptr,a.ldn[4], Ahs,Als, acc, cb,lr,lq);
    __syncthreads();
    #pragma unroll
    for (int rg=0;rg<4;rg++){
        int rbase = rg*16+lq*4;
        #pragma unroll
        for (int j=0;j<4;j++){
            int col = cb+j*16+lr;
            #pragma unroll
            for (int r=0;r<4;r++){
                int row = rbase+r;
                float v = acc[rg][j][r]*IS2;
                if (col<217){
                    v *= (float)a.fac[3][(size_t)(bm+row)*217+col];
                    bf16 h=(bf16)v;
                    Ahs[row*AS+col]=h; Als[row*AS+col]=(bf16)(v-(float)h);
                } else {
                    detl[row][col-217]=v;
                    Ahs[row*AS+col]=(bf16)0.f; Als[row*AS+col]=(bf16)0.f;
                }
            }
        }
    }
    __syncthreads();
    BLAYER(3,7,a.fac[2],256)
    BLAYER(2,8,a.fac[1],256)
    BLAYER(1,8,a.fac[0],256)
    #undef BLAYER
    // din0 (cols<39)
    mlp_gemm<2,AS,8>(a.nh[0],nullptr,a.ldn[0], Ahs,Als, acc, cb,lr,lq);
    __syncthreads();   // all waves done reading Als -> safe to alias as dn0
    #pragma unroll
    for (int rg=0;rg<4;rg++){
        int rbase = rg*16+lq*4;
        #pragma unroll
        for (int j=0;j<4;j++){
            int col = cb+j*16+lr;
            if (col<39){
                #pragma unroll
                for (int r=0;r<4;r++) dn0[(rbase+r)*40+col] = acc[rg][j][r];
            }
        }
    }
    __syncthreads();
    if (tid<64){
        int pg = a.offp + bm + tid;
        int rI = pg>>7; int sI = pg&127;
        float zv = a.zA[rI*128+sI];
        float dist = (sI<127) ? a.zA[rI*128+sI+1]-zv : 0.03125f;
        float pm = zv + 0.5f*dist;
        float px = a.ro[3*rI+0]+a.rd[3*rI+0]*pm;
        float py = a.ro[3*rI+1]+a.rd[3*rI+1]*pm;
        float pz = a.ro[3*rI+2]+a.rd[3*rI+2]*pm;
        float g0=dn0[tid*40+0]+detl[tid][0];
        float g1=dn0[tid*40+1]+detl[tid][1];
        float g2=dn0[tid*40+2]+detl[tid][2];
        float fq=1.f;
        #pragma unroll
        for (int q=0;q<6;q++){
            int base=3+6*q;
            float ds0=dn0[tid*40+base+0]+detl[tid][base+0];
            float ds1=dn0[tid*40+base+1]+detl[tid][base+1];
            float ds2=dn0[tid*40+base+2]+detl[tid][base+2];
            float dc0=dn0[tid*40+base+3]+detl[tid][base+3];
            float dc1=dn0[tid*40+base+4]+detl[tid][base+4];
            float dc2=dn0[tid*40+base+5]+detl[tid][base+5];
            g0 += fq*(__cosf(fq*px)*ds0 - __sinf(fq*px)*dc0);
            g1 += fq*(__cosf(fq*py)*ds1 - __sinf(fq*py)*dc1);
            g2 += fq*(__cosf(fq*pz)*ds2 - __sinf(fq*pz)*dc2);
            fq *= 2.f;
        }
        float dx=a.rd[3*rI],dy=a.rd[3*rI+1],dz=a.rd[3*rI+2];
        a.tcos[pg] = dx*g0+dy*g1+dz*g2;
        float nm = fmaxf(sqrtf(g0*g0+g1*g1+g2*g2), 1e-6f);
        float vals[9] = {px,py,pz,dx,dy,dz,g0/nm,g1/nm,g2/nm};
        bf16* ch = a.cinH + (size_t)(bm+tid)*272;
        bf16* cl = a.cinL + (size_t)(bm+tid)*272;
        #pragma unroll
        for (int c=0;c<9;c++){
            float v=vals[c]; bf16 h=(bf16)v;
            ch[c]=h; cl[c]=(bf16)(v-(float)h);
        }
        #pragma unroll
        for (int c=265;c<272;c++){ ch[c]=(bf16)0.f; cl[c]=(bf16)0.f; }
    }
}

// ---------- fused color MLP ----------
struct ColArgs {
    const bf16 *cinH, *cinL;
    const bf16 *w0h,*w0l; int ld0; const float* b0;
    const bf16 *w1h,*w1l; const float* b1;
    const float* w2; const float* b2;
    float* rgb;
};

__global__ __launch_bounds__(256,2) void k_col(ColArgs a)
{
    __shared__ bf16 Ahs[64*AS2], Als[64*AS2];
    __shared__ float W2s[256*3];
    const int tid=threadIdx.x, wid=tid>>6, lane=tid&63, lr=lane&15, lq=lane>>4;
    const int cb=wid*64;
    const int bm = blockIdx.x*64;

    W2s[tid*3]=a.w2[tid*3]; W2s[tid*3+1]=a.w2[tid*3+1]; W2s[tid*3+2]=a.w2[tid*3+2];
    // stage cin (hi/lo) into LDS: 4 parts = 2 planes x 2 col-chunks of 136
    {
        int row = tid&63, sel = tid>>6;
        int plane = sel>>1, c0 = (sel&1)*136;
        const bf16* src = plane? a.cinL : a.cinH;
        bf16* dst = plane? Als : Ahs;
        const bf16* s = src + (size_t)(bm+row)*272 + c0;
        bf16* d = dst + row*AS2 + c0;
        #pragma unroll
        for (int v=0;v<17;v++) *(bf16x8*)(d+v*8) = *(const bf16x8*)(s+v*8);
        if (sel&1){
            bf16x8 z = {};
            bf16* zd = dst + row*AS2 + 272;
            #pragma unroll
            for (int v=0;v<3;v++) *(bf16x8*)(zd+v*8) = z;
        }
    }
    __syncthreads();

    floatx4 acc[4][4];
    auto wb_relu = [&](const float* bias){
        #pragma unroll
        for (int rg=0;rg<4;rg++){
            int rbase = rg*16+lq*4;
            #pragma unroll
            for (int j=0;j<4;j++){
                int col = cb+j*16+lr;
                float bv = bias[col];
                #pragma unroll
                for (int r=0;r<4;r++){
                    int row = rbase+r;
                    float v = fmaxf(acc[rg][j][r]+bv, 0.f);
                    bf16 h=(bf16)v;
                    Ahs[row*AS2+col]=h; Als[row*AS2+col]=(bf16)(v-(float)h);
                }
            }
        }
    };
    mlp_gemm<3,AS2,9>(a.w0h,a.w0l,a.ld0, Ahs,Als, acc, cb,lr,lq);
    __syncthreads();
    wb_relu(a.b0);
    __syncthreads();
    mlp_gemm<3,AS2,8>(a.w1h,a.w1l,256, Ahs,Als, acc, cb,lr,lq);
    __syncthreads();
    wb_relu(a.b1);
    __syncthreads();
    // rgb = sigmoid(h @ cw2 + cb2)   (4 lanes per row)
    {
        int row = wid*16 + (lane>>2);
        int kc  = (lane&3)*64;
        const bf16* ah=&Ahs[row*AS2+kc]; const bf16* al=&Als[row*AS2+kc];
        float s0=0.f,s1=0.f,s2=0.f;
        #pragma unroll
        for (int c=0;c<8;c++){
            bf16x8 vh=*(const bf16x8*)(ah+c*8), vl=*(const bf16x8*)(al+c*8);
            #pragma unroll
            for (int j=0;j<8;j++){
                float fv = (float)vh[j]+(float)vl[j];
                int k = kc+c*8+j;
                s0 += fv*W2s[k*3]; s1 += fv*W2s[k*3+1]; s2 += fv*W2s[k*3+2];
            }
        }
        #pragma unroll
        for (int m=1;m<4;m<<=1){
            s0 += __shfl_xor(s0,m,64); s1 += __shfl_xor(s1,m,64); s2 += __shfl_xor(s2,m,64);
        }
        if ((lane&3)==0){
            float* o = a.rgb + (size_t)(bm+row)*3;
            o[0]=sigm(s0+a.b2[0]); o[1]=sigm(s1+a.b2[1]); o[2]=sigm(s2+a.b2[2]);
        }
    }
}

// ---------- weight conversion ----------
struct ConvDesc { const float* src; bf16 *th, *tl, *nh; int K, N, ldt, ldn; };
struct ConvArgs { ConvDesc d[11]; };
__global__ void k_conv(ConvArgs a){
    ConvDesc cd = a.d[blockIdx.y];
    int idx = blockIdx.x*256+threadIdx.x;
    if (idx >= cd.K*cd.N) return;
    int k = idx / cd.N, n = idx - k*cd.N;
    float v = cd.src[idx];
    bf16 h = (bf16)v;
    cd.th[(size_t)n*cd.ldt + k] = h;
    cd.tl[(size_t)n*cd.ldt + k] = (bf16)(v - (float)h);
    if (cd.nh) cd.nh[(size_t)k*cd.ldn + n] = h;
}

// ---------- small kernels ----------
__global__ void k_ray_setup(const float* __restrict__ o, const float* __restrict__ d,
                            float* __restrict__ z)
{
    int r = blockIdx.x; int i = threadIdx.x;
    float ox=o[3*r],oy=o[3*r+1],oz=o[3*r+2];
    float dx=d[3*r],dy=d[3*r+1],dz=d[3*r+2];
    float a = dx*dx+dy*dy+dz*dz;
    float b = 2.f*(ox*dx+oy*dy+oz*dz);
    float mid = -b/(2.f*a);
    float nearv = fmaxf(mid-1.f, 0.05f);
    float farv = mid+1.f;
    z[r*128+i] = nearv + (farv-nearv)*((float)i/63.f);
}

__global__ void k_upsample(const float* __restrict__ o, const float* __restrict__ d,
                           const float* __restrict__ z, const float* __restrict__ sdf,
                           int S, float inv_s, float* __restrict__ new_z)
{
    int r = blockIdx.x*64+threadIdx.x; if (r>=NR) return;
    const float* zr = z + r*128;
    const float* sr = sdf + r*128;
    float ox=o[3*r],oy=o[3*r+1],oz=o[3*r+2];
    float dx=d[3*r],dy=d[3*r+1],dz=d[3*r+2];
    float w[128];
    float cdf[129];
    float wsum=0.f, T=1.f, raw_prev=0.f;
    float z0 = zr[0];
    float px=ox+dx*z0, py=oy+dy*z0, pz=oz+dz*z0;
    float r0 = sqrtf(px*px+py*py+pz*pz);
    for (int i=0;i<S-1;i++){
        float z1 = zr[i+1];
        float qx=ox+dx*z1, qy=oy+dy*z1, qz=oz+dz*z1;
        float r1 = sqrtf(qx*qx+qy*qy+qz*qz);
        bool inside = (r0<1.f)||(r1<1.f);
        float s0=sr[i], s1=sr[i+1];
        float zc = zr[i];
        float mid_sdf = 0.5f*(s0+s1);
        float raw = (s1-s0)/(z1-zc+1e-5f);
        float cv = fminf(raw, (i==0)?0.f:raw_prev);
        raw_prev = raw;
        cv = fminf(fmaxf(cv,-1000.f),0.f);
        if (!inside) cv = 0.f;
        float dist = z1-zc;
        float pe = mid_sdf - cv*dist*0.5f;
        float ne = mid_sdf + cv*dist*0.5f;
        float pc = sigm(pe*inv_s), nc = sigm(ne*inv_s);
        float alpha = (pc-nc+1e-5f)/(pc+1e-5f);
        float wi = alpha*T;
        T *= (1.f-alpha+1e-7f);
        w[i] = wi + 1e-5f;
        wsum += w[i];
        r0 = r1;
    }
    cdf[0]=0.f;
    float c=0.f;
    for (int i=0;i<S-1;i++){ c += w[i]/wsum; cdf[i+1]=c; }
    for (int j=0;j<16;j++){
        float u = 0.03125f + 0.0625f*(float)j;
        int lo=0, hi=S;
        while (lo<hi){ int m=(lo+hi)>>1; if (cdf[m]<=u) lo=m+1; else hi=m; }
        int idx = lo;
        int below = idx-1; if (below<0) below=0; if (below>S-1) below=S-1;
        int above = idx;   if (above>S-1) above=S-1;
        float c0=cdf[below], c1=cdf[above];
        float b0=zr[below], b1=zr[above];
        float dn = c1-c0; if (dn<1e-5f) dn=1.f;
        new_z[r*16+j] = b0 + (u-c0)/dn*(b1-b0);
    }
}

__global__ void k_merge(const float* __restrict__ zin, const float* __restrict__ sin_,
                        const float* __restrict__ nz, const float* __restrict__ nsdf,
                        int S, float* __restrict__ zout, float* __restrict__ sout)
{
    int r = blockIdx.x*64+threadIdx.x; if (r>=NR) return;
    const float* az = zin + r*128; const float* as = sin_ + r*128;
    const float* bz = nz + r*16;   const float* bs = nsdf + r*16;
    int i=0, j=0;
    for (int k=0;k<S+16;k++){
        bool takeA = (j>=16) || (i<S && az[i] <= bz[j]);
        if (takeA){ zout[r*128+k]=az[i]; sout[r*128+k]=as[i]; i++; }
        else      { zout[r*128+k]=bz[j]; sout[r*128+k]=bs[j]; j++; }
    }
}

__global__ void k_composite(const float* __restrict__ z, const float* __restrict__ sdfv,
                            const float* __restrict__ tcos, const float* __restrict__ rgbs,
                            const float* __restrict__ var, float* __restrict__ out)
{
    int r = blockIdx.x*64+threadIdx.x; if (r>=NR) return;
    float inv_s = expf(var[0]*10.f);
    inv_s = fminf(fmaxf(inv_s,1e-6f),1e6f);
    float T=1.f, c0=0.f, c1=0.f, c2=0.f;
    for (int sI=0;sI<128;sI++){
        float zv = z[r*128+sI];
        float dist = (sI<127)? z[r*128+sI+1]-zv : 0.03125f;
        float sd = sdfv[r*128+sI];
        float ic = fminf(tcos[r*128+sI], 0.f);
        float ep = sd - ic*dist*0.5f, en = sd + ic*dist*0.5f;
        float pc = sigm(ep*inv_s), nc = sigm(en*inv_s);
        float al = (pc-nc+1e-5f)/(pc+1e-5f);
        al = fminf(fmaxf(al,0.f),1.f);
        float wgt = al*T;
        T *= (1.f-al+1e-7f);
        c0 += wgt*rgbs[(size_t)(r*128+sI)*3+0];
        c1 += wgt*rgbs[(size_t)(r*128+sI)*3+1];
        c2 += wgt*rgbs[(size_t)(r*128+sI)*3+2];
    }
    out[3*r+0]=c0; out[3*r+1]=c1; out[3*r+2]=c2;
}

// ---------- host ----------
static inline size_t ru8(size_t x){ return (x+7)&~(size_t)7; }

extern "C" void kernel_launch(void* const* d_in, const int* in_sizes, int n_in,
                              void* d_out, int out_size, void* d_ws, size_t ws_size,
                              hipStream_t stream)
{
    const float* rays_o = (const float*)d_in[0];
    const float* rays_d = (const float*)d_in[1];
    const float* sw[9]; const float* sb[9];
    for (int l=0;l<9;l++){ sw[l]=(const float*)d_in[2+2*l]; sb[l]=(const float*)d_in[3+2*l]; }
    const float* cw0=(const float*)d_in[20]; const float* cb0=(const float*)d_in[21];
    const float* cw1=(const float*)d_in[22]; const float* cb1=(const float*)d_in[23];
    const float* cw2=(const float*)d_in[24]; const float* cb2=(const float*)d_in[25];
    const float* varp=(const float*)d_in[26];
    float* out = (float*)d_out;
    float* f = (float*)d_ws;
    size_t nf = ws_size/sizeof(float);

    size_t off = 0;
    auto AF = [&](size_t n){ float* p = f+off; off += n; return p; };
    float* zA   = AF(NR*128);
    float* zB   = AF(NR*128);
    float* sA   = AF(NR*128);
    float* sB   = AF(NR*128);
    float* nzb  = AF(NR*16);
    float* nsb  = AF(NR*16);
    float* sdfF = AF(NR*128);
    float* tcos = AF(NR*128);
    float* rgbs = AF((size_t)NR*128*3);

    off = (off+3)&~(size_t)3;   // 16B-align the bf16 pool
    bf16* wb = (bf16*)(f+off);
    size_t wboff = 0;
    auto AB = [&](size_t n){ n = ru8(n)+32; bf16* p = wb+wboff; wboff += n; return p; };

    const int inD[9]  = {39,256,256,256,256,256,256,256,256};
    const int outD[9] = {256,256,256,217,256,256,256,256,257};
    const bf16 *tH[11], *tL[11]; int ldt[11];
    const bf16 *nH[8]; int ldn_[8];
    ConvArgs ca;
    for (int l=0;l<9;l++){
        int K=inD[l], N=outD[l];
        int ld = (int)ru8(K);
        bf16* th = AB((size_t)N*ld);
        bf16* tl = AB((size_t)N*ld);
        bf16* nh = nullptr; int ldn = 0;
        if (l<8){ ldn = (int)ru8(N); nh = AB((size_t)K*ldn); nH[l]=nh; ldn_[l]=ldn; }
        tH[l]=th; tL[l]=tl; ldt[l]=ld;
        ca.d[l] = ConvDesc{ sw[l], th, tl, nh, K, N, ld, ldn };
    }
    {
        int K=265, N=256, ld=(int)ru8(K); // 272
        bf16* th = AB((size_t)N*ld); bf16* tl = AB((size_t)N*ld);
        tH[9]=th; tL[9]=tl; ldt[9]=ld;
        ca.d[9] = ConvDesc{ cw0, th, tl, nullptr, K, N, ld, 0 };
        K=256; N=256; ld=256;
        bf16* th1 = AB((size_t)N*ld); bf16* tl1 = AB((size_t)N*ld);
        tH[10]=th1; tL[10]=tl1; ldt[10]=ld;
        ca.d[10] = ConvDesc{ cw1, th1, tl1, nullptr, K, N, ld, 0 };
    }
    off += (wboff+1)/2;
    off = (off+3)&~(size_t)3;

    // chunk region (fac planes + cin planes only)
    size_t avail = (nf > off) ? nf - off : 0;
    int CHF = 131072;
    while (CHF > 1024 && (size_t)CHF*1280 > avail) CHF >>= 1;

    bf16* cb2_ = (bf16*)(f+off);
    size_t bo2 = 0;
    auto B3 = [&](size_t n){ n=ru8(n); bf16* p=cb2_+bo2; bo2+=n; return p; };
    bf16* facP[8];
    for (int l=0;l<8;l++){
        int ld = (l==3)? 217 : 256;
        facP[l] = B3((size_t)CHF*ld);
    }
    bf16* cinH = B3((size_t)CHF*272);
    bf16* cinL = B3((size_t)CHF*272);

    // ---- weight conversion ----
    k_conv<<<dim3(266,11),256,0,stream>>>(ca);
    // ---- rays + base z ----
    k_ray_setup<<<NR,64,0,stream>>>(rays_o, rays_d, zA);

    FwdArgs fa{};
    for (int l=0;l<9;l++){ fa.wh[l]=tH[l]; fa.wl[l]=tL[l]; fa.wld[l]=ldt[l]; fa.bias[l]=sb[l]; }
    fa.w8col = sw[8]; fa.ro = rays_o; fa.rd = rays_d;

    // ---- sampling: base (64 samples/ray) ----
    {
        FwdArgs s = fa;
        s.zbuf=zA; s.zper=64; s.zstr=128; s.pmode=0;
        s.sdfo = sA; s.soff=0; s.sper=64; s.sstr=128;
        k_fwd<0><<<65536/64,256,0,stream>>>(s);
    }
    // ---- 4 up-sample steps ----
    for (int it=0; it<4; it++){
        int S = 64 + 16*it;
        float* zsrc = (it&1)? zB : zA;  float* ssrc = (it&1)? sB : sA;
        float* zdst = (it&1)? zA : zB;  float* sdst = (it&1)? sA : sB;
        float inv_s = 64.f * (float)(1<<it);
        k_upsample<<<NR/64,64,0,stream>>>(rays_o, rays_d, zsrc, ssrc, S, inv_s, nzb);
        FwdArgs s = fa;
        s.zbuf=nzb; s.zper=16; s.zstr=16; s.pmode=0;
        s.sdfo = nsb; s.soff=0; s.sper=16; s.sstr=16;
        k_fwd<0><<<(NR*16)/64,256,0,stream>>>(s);
        k_merge<<<NR/64,64,0,stream>>>(zsrc, ssrc, nzb, nsb, S, zdst, sdst);
    }
    // final z in zA

    // ---- final phase ----
    for (int offp=0; offp<NR*128; offp+=CHF){
        int n = CHF;
        FwdArgs s = fa;
        s.zbuf=zA; s.pmode=1;
        s.sdfo = sdfF; s.soff=offp; s.sper=1; s.sstr=1;
        s.cinH=cinH; s.cinL=cinL;
        for (int l=0;l<8;l++) s.fac[l]=facP[l];
        k_fwd<1><<<n/64,256,0,stream>>>(s);

        BwdArgs b{};
        for (int l=0;l<8;l++){ b.nh[l]=nH[l]; b.ldn[l]=ldn_[l]; b.fac[l]=facP[l]; }
        b.w8col = sw[8]; b.zA = zA; b.ro = rays_o; b.rd = rays_d;
        b.cinH=cinH; b.cinL=cinL; b.tcos=tcos; b.offp=offp;
        k_bwd<<<n/64,256,0,stream>>>(b);

        ColArgs c{};
        c.cinH=cinH; c.cinL=cinL;
        c.w0h=tH[9]; c.w0l=tL[9]; c.ld0=ldt[9]; c.b0=cb0;
        c.w1h=tH[10]; c.w1l=tL[10]; c.b1=cb1;
        c.w2=cw2; c.b2=cb2; c.rgb = rgbs + (size_t)offp*3;
        k_col<<<n/64,256,0,stream>>>(c);
    }
    k_composite<<<NR/64,64,0,stream>>>(zA, sdfF, tcos, rgbs, varp, out);
}